// Round 9
// baseline (111.220 us; speedup 1.0000x reference)
//
#include <hip/hip_runtime.h>
#include <hip/hip_fp16.h>

// BEVTrans: out[b, c*5+h, d, w] = bilinear_sample(X[b,c], ix(b,w,h,d), iy(b,w,h,d))
//   (calib row 2 is exactly [0,0,1] in the reference -> z = dz)
// X: [4,256,96,320] f32, calib: [4,3,3] f32, out: [4,1280,100,100] f32
//
// R8: locality inversion. One block per (b,c); the block walks ALL 50K
// positions in (d,h,w) order, so consecutive iterations reuse the same X rows
// and each 123KB slice is pulled through L1 ~once (R4's layout re-fetched it
// from L2 ~7x across 196 position-blocks). Coord table compressed to 16B/pos
// {off, outoff, half4 w} = ONE coalesced dwordx4 per position. Branchless:
// clamped offsets always valid, OOB positions have zero weights. Unroll-4
// keeps 4 table loads + 16 gathers in flight.

#define W_IN  320
#define H_IN  96
#define SLICE (H_IN * W_IN)     // 30720 floats per (b,c)
#define NPOS  50000
#define UNROLL 4

struct __align__(16) Entry {
    int off;            // clamped slice offset (yc*320+xc), always valid
    int outoff;         // h*10000 + d*100 + w
    unsigned int w01;   // half2(w00, w01)
    unsigned int w23;   // half2(w10, w11)
};

union H2U { unsigned int u; __half2 h; };

__global__ __launch_bounds__(256) void coord_kernel(const float* __restrict__ calib,
                                                    Entry* __restrict__ tbl) {
    const int b = blockIdx.z;
    const int t = blockIdx.x * 256 + threadIdx.x;
    if (t >= NPOS) return;

    const int d = t / 500;
    const int r = t - d * 500;
    const int h = r / 100;
    const int w = r - h * 100;

    const float* cb = calib + b * 9;
    const float c00 = cb[0], c01 = cb[1], c02 = cb[2];
    const float c10 = cb[3], c11 = cb[4], c12 = cb[5];

    const float wxv = -9.9f + 0.2f * (float)w;
    const float hyv = -3.0f + (float)h;
    const float dzv = 0.1f + 0.2f * (float)d;
    const float inv = 1.0f / dzv;

    const float ix = 319.0f * inv * (c00 * wxv + c01 * hyv + c02 * dzv);
    const float iy =  95.0f * inv * (c10 * wxv + c11 * hyv + c12 * dzv);
    const float fx0 = floorf(ix), fy0 = floorf(iy);
    const int ix0 = (int)fx0, iy0 = (int)fy0;
    const float ax = ix - fx0, ay = iy - fy0;

    // shifted-weight border handling: weights apply to (xc, xc+1), (yc, yc+1)
    float a0, a1, b0, b1;
    if (ix0 >= 0 && ix0 <= 318)      { a0 = 1.0f - ax; a1 = ax; }
    else if (ix0 == -1)              { a0 = ax;        a1 = 0.0f; }
    else if (ix0 == 319)             { a0 = 0.0f;      a1 = 1.0f - ax; }
    else                             { a0 = 0.0f;      a1 = 0.0f; }
    if (iy0 >= 0 && iy0 <= 94)       { b0 = 1.0f - ay; b1 = ay; }
    else if (iy0 == -1)              { b0 = ay;        b1 = 0.0f; }
    else if (iy0 == 95)              { b0 = 0.0f;      b1 = 1.0f - ay; }
    else                             { b0 = 0.0f;      b1 = 0.0f; }

    const int xc = min(max(ix0, 0), 318);
    const int yc = min(max(iy0, 0), 94);

    Entry e;
    e.off    = yc * W_IN + xc;
    e.outoff = h * 10000 + d * 100 + w;
    H2U p0, p1;
    p0.h = __floats2half2_rn(a0 * b0, a1 * b0);
    p1.h = __floats2half2_rn(a0 * b1, a1 * b1);
    e.w01 = p0.u;
    e.w23 = p1.u;
    tbl[b * NPOS + t] = e;
}

typedef int i32x4 __attribute__((ext_vector_type(4)));

__global__ __launch_bounds__(256, 4) void gather_kernel(const float* __restrict__ X,
                                                        const Entry* __restrict__ tbl,
                                                        float* __restrict__ out) {
    const int bc = blockIdx.x;             // b*256 + c
    const int b  = bc >> 8;

    const float* __restrict__ Xs = X + (size_t)bc * SLICE;
    const Entry* __restrict__ tb = tbl + b * NPOS;
    float* __restrict__ oc = out + (size_t)b * 12800000 + (size_t)(bc & 255) * 50000;

    for (int t0 = 0; t0 < NPOS; t0 += 256 * UNROLL) {
        int   tv[UNROLL];
        Entry e[UNROLL];
        // phase 1: table loads (coalesced dwordx4)
        #pragma unroll
        for (int k = 0; k < UNROLL; ++k) {
            tv[k] = t0 + (int)threadIdx.x + k * 256;
            const int tc = min(tv[k], NPOS - 1);
            e[k] = tb[tc];
        }
        // phase 2: gathers (16 in flight)
        float g00[UNROLL], g01[UNROLL], g10[UNROLL], g11[UNROLL];
        #pragma unroll
        for (int k = 0; k < UNROLL; ++k) {
            const float* p = Xs + e[k].off;
            g00[k] = p[0];
            g01[k] = p[1];
            g10[k] = p[320];
            g11[k] = p[321];
        }
        // phase 3: combine + guarded store
        #pragma unroll
        for (int k = 0; k < UNROLL; ++k) {
            H2U u0, u1; u0.u = e[k].w01; u1.u = e[k].w23;
            const float2 wa = __half22float2(u0.h);
            const float2 wb = __half22float2(u1.h);
            float v = wa.x * g00[k];
            v = fmaf(wa.y, g01[k], v);
            v = fmaf(wb.x, g10[k], v);
            v = fmaf(wb.y, g11[k], v);
            if (tv[k] < NPOS)
                __builtin_nontemporal_store(v, oc + e[k].outoff);
        }
    }
}

extern "C" void kernel_launch(void* const* d_in, const int* in_sizes, int n_in,
                              void* d_out, int out_size, void* d_ws, size_t ws_size,
                              hipStream_t stream) {
    const float* X     = (const float*)d_in[0];   // [4,256,96,320]
    const float* calib = (const float*)d_in[1];   // [4,3,3]
    float* out = (float*)d_out;                   // [4,1280,100,100]

    Entry* tbl = (Entry*)d_ws;                    // 4*50000*16 = 3.2 MB

    dim3 g1((NPOS + 255) / 256, 1, 4);
    coord_kernel<<<g1, dim3(256), 0, stream>>>(calib, tbl);

    gather_kernel<<<dim3(1024), dim3(256), 0, stream>>>(X, tbl, out);
}

// Round 10
// 95.888 us; speedup vs baseline: 1.1599x; 1.1599x over previous
//
#include <hip/hip_runtime.h>
#include <hip/hip_fp16.h>

// BEVTrans: out[b, c*5+h, d, w] = bilinear_sample(X[b,c], ix(b,w,h,d), iy(b,w,h,d))
//   (calib row 2 is exactly [0,0,1] in the reference -> z = dz)
// X: [4,256,96,320] f32, calib: [4,3,3] f32, out: [4,1280,100,100] f32
//
// R9 = R4 structure (best so far, 82.3us) + two instruction-count cuts on the
// VMEM pipe (the measured limiter):
//  1. paired-corner loads: (x0,x0+1) adjacent floats -> ONE 4B-aligned
//     global_load_dwordx2 per row (gfx9+ unaligned-access-mode makes this
//     legal); 4 gathers/sample -> 2. 204.8M -> 102.4M gather instrs.
//  2. 16B coord Entry {off, outoff, half2 w01, half2 w23}: 1 dwordx4 table
//     load per position instead of int2+float4.

#define W_IN  320
#define H_IN  96
#define SLICE (H_IN * W_IN)     // 30720 floats per (b,c)
#define NPOS  50000
#define CG    16                // channels per thread

typedef float f32x2 __attribute__((ext_vector_type(2), aligned(4)));

struct __align__(16) Entry {
    int off;            // clamped slice offset (yc*320+xc); off+321 always in-bounds
    int outoff;         // h*10000 + d*100 + w
    unsigned int w01;   // half2(w00, w01)
    unsigned int w23;   // half2(w10, w11)
};

union H2U { unsigned int u; __half2 h; };

__global__ __launch_bounds__(256) void coord_kernel(const float* __restrict__ calib,
                                                    Entry* __restrict__ tbl) {
    const int b = blockIdx.z;
    const int t = blockIdx.x * 256 + threadIdx.x;
    if (t >= NPOS) return;

    const int d = t / 500;
    const int r = t - d * 500;
    const int h = r / 100;
    const int w = r - h * 100;

    const float* cb = calib + b * 9;
    const float c00 = cb[0], c01 = cb[1], c02 = cb[2];
    const float c10 = cb[3], c11 = cb[4], c12 = cb[5];

    const float wxv = -9.9f + 0.2f * (float)w;
    const float hyv = -3.0f + (float)h;
    const float dzv = 0.1f + 0.2f * (float)d;
    const float inv = 1.0f / dzv;

    const float ix = 319.0f * inv * (c00 * wxv + c01 * hyv + c02 * dzv);
    const float iy =  95.0f * inv * (c10 * wxv + c11 * hyv + c12 * dzv);
    const float fx0 = floorf(ix), fy0 = floorf(iy);
    const int ix0 = (int)fx0, iy0 = (int)fy0;
    const float ax = ix - fx0, ay = iy - fy0;

    // shifted-weight border handling: weights apply to (xc, xc+1), (yc, yc+1)
    float a0, a1, b0, b1;
    if (ix0 >= 0 && ix0 <= 318)      { a0 = 1.0f - ax; a1 = ax; }
    else if (ix0 == -1)              { a0 = ax;        a1 = 0.0f; }
    else if (ix0 == 319)             { a0 = 0.0f;      a1 = 1.0f - ax; }
    else                             { a0 = 0.0f;      a1 = 0.0f; }
    if (iy0 >= 0 && iy0 <= 94)       { b0 = 1.0f - ay; b1 = ay; }
    else if (iy0 == -1)              { b0 = ay;        b1 = 0.0f; }
    else if (iy0 == 95)              { b0 = 0.0f;      b1 = 1.0f - ay; }
    else                             { b0 = 0.0f;      b1 = 0.0f; }

    const int xc = min(max(ix0, 0), 318);
    const int yc = min(max(iy0, 0), 94);

    Entry e;
    e.off    = yc * W_IN + xc;
    e.outoff = h * 10000 + d * 100 + w;
    H2U p0, p1;
    p0.h = __floats2half2_rn(a0 * b0, a1 * b0);
    p1.h = __floats2half2_rn(a0 * b1, a1 * b1);
    e.w01 = p0.u;
    e.w23 = p1.u;
    tbl[b * NPOS + t] = e;
}

__global__ __launch_bounds__(256) void gather_kernel(const float* __restrict__ X,
                                                     const Entry* __restrict__ tbl,
                                                     float* __restrict__ out) {
    const int bcg = blockIdx.y;            // b*16 + channel_group
    const int b   = bcg >> 4;
    const int c0  = (bcg & 15) * CG;
    const int t   = blockIdx.x * 256 + threadIdx.x;
    if (t >= NPOS) return;

    const Entry e = tbl[b * NPOS + t];

    H2U u0, u1; u0.u = e.w01; u1.u = e.w23;
    const float2 wa = __half22float2(u0.h);
    const float2 wb = __half22float2(u1.h);

    const float* Xc = X + ((size_t)b * 256 + (size_t)c0) * SLICE + e.off;
    float* oc = out + (size_t)b * 12800000 + (size_t)c0 * 50000 + e.outoff;

    // phase 1: 32 paired-corner loads (dwordx2), all in flight
    f32x2 g0[CG], g1[CG];
    #pragma unroll
    for (int cc = 0; cc < CG; ++cc) {
        const float* p = Xc + (size_t)cc * SLICE;
        g0[cc] = *reinterpret_cast<const f32x2*>(p);          // x0, x0+1   (row y0)
        g1[cc] = *reinterpret_cast<const f32x2*>(p + 320);    // x0, x0+1   (row y1)
    }
    // phase 2: combine + store
    #pragma unroll
    for (int cc = 0; cc < CG; ++cc) {
        float v = wa.x * g0[cc].x;
        v = fmaf(wa.y, g0[cc].y, v);
        v = fmaf(wb.x, g1[cc].x, v);
        v = fmaf(wb.y, g1[cc].y, v);
        __builtin_nontemporal_store(v, oc + (size_t)cc * 50000);
    }
}

extern "C" void kernel_launch(void* const* d_in, const int* in_sizes, int n_in,
                              void* d_out, int out_size, void* d_ws, size_t ws_size,
                              hipStream_t stream) {
    const float* X     = (const float*)d_in[0];   // [4,256,96,320]
    const float* calib = (const float*)d_in[1];   // [4,3,3]
    float* out = (float*)d_out;                   // [4,1280,100,100]

    Entry* tbl = (Entry*)d_ws;                    // 4*50000*16 = 3.2 MB

    dim3 g1((NPOS + 255) / 256, 1, 4);
    coord_kernel<<<g1, dim3(256), 0, stream>>>(calib, tbl);

    dim3 g2((NPOS + 255) / 256, 64);              // 196 x (4 batches * 16 groups)
    gather_kernel<<<g2, dim3(256), 0, stream>>>(X, tbl, out);
}

// Round 11
// 72.024 us; speedup vs baseline: 1.5442x; 1.3313x over previous
//
#include <hip/hip_runtime.h>

// BEVTrans: out[b, c*5+h, d, w] = bilinear_sample(X[b,c], ix(b,w,h,d), iy(b,w,h,d))
//   (calib row 2 is exactly [0,0,1] in the reference -> z = dz)
// X: [4,256,96,320] f32, calib: [4,3,3] f32, out: [4,1280,100,100] f32
//
// R10 = R4 structure (best: inline coords, scalar gathers, phase-split MLP)
// with per-output overhead halved: each thread owns 2 consecutive w (pairs
// never straddle a row; 100 even) x CG=8 channels -> dwordx2 nt stores
// (store instrs 800K->400K), coord math amortized over 16 outputs like R4,
// 64 loads in flight per thread, single kernel (no table, no 2nd launch).

#define W_IN  320
#define H_IN  96
#define SLICE (H_IN * W_IN)     // 30720 floats per (b,c)
#define CG    8                 // channels per thread
#define NP2   25000             // 50000 positions / 2 per thread

typedef float f32x2 __attribute__((ext_vector_type(2)));

__global__ __launch_bounds__(256) void bev_kernel(const float* __restrict__ X,
                                                  const float* __restrict__ calib,
                                                  float* __restrict__ out) {
    const int bcg = blockIdx.y;            // b*32 + channel_group
    const int b   = bcg >> 5;
    const int c0  = (bcg & 31) * CG;
    const int t   = blockIdx.x * 256 + threadIdx.x;   // pair index
    if (t >= NP2) return;

    const int item = t * 2;                // 2 consecutive w, same (d,h)
    const int d = item / 500;
    const int r = item - d * 500;
    const int h = r / 100;
    const int w0 = r - h * 100;

    const float* cb = calib + b * 9;
    const float c00 = cb[0], c01 = cb[1], c02 = cb[2];
    const float c10 = cb[3], c11 = cb[4], c12 = cb[5];

    const float hyv = -3.0f + (float)h;
    const float dzv = 0.1f + 0.2f * (float)d;
    const float inv = 1.0f / dzv;

    int   off[2];
    float W00[2], W01[2], W10[2], W11[2];
    float wsum = 0.0f;
    #pragma unroll
    for (int j = 0; j < 2; ++j) {
        const float wxv = -9.9f + 0.2f * (float)(w0 + j);
        const float ix = 319.0f * inv * (c00 * wxv + c01 * hyv + c02 * dzv);
        const float iy =  95.0f * inv * (c10 * wxv + c11 * hyv + c12 * dzv);
        const float fx0 = floorf(ix), fy0 = floorf(iy);
        const int ix0 = (int)fx0, iy0 = (int)fy0;
        const float ax = ix - fx0, ay = iy - fy0;

        // shifted-weight border handling: weights apply to (xc,xc+1),(yc,yc+1)
        float a0, a1, b0, b1;
        if (ix0 >= 0 && ix0 <= 318)      { a0 = 1.0f - ax; a1 = ax; }
        else if (ix0 == -1)              { a0 = ax;        a1 = 0.0f; }
        else if (ix0 == 319)             { a0 = 0.0f;      a1 = 1.0f - ax; }
        else                             { a0 = 0.0f;      a1 = 0.0f; }
        if (iy0 >= 0 && iy0 <= 94)       { b0 = 1.0f - ay; b1 = ay; }
        else if (iy0 == -1)              { b0 = ay;        b1 = 0.0f; }
        else if (iy0 == 95)              { b0 = 0.0f;      b1 = 1.0f - ay; }
        else                             { b0 = 0.0f;      b1 = 0.0f; }

        const int xc = min(max(ix0, 0), 318);
        const int yc = min(max(iy0, 0), 94);
        off[j] = yc * W_IN + xc;
        W00[j] = a0 * b0;  W01[j] = a1 * b0;
        W10[j] = a0 * b1;  W11[j] = a1 * b1;
        wsum += W00[j] + W01[j] + W10[j] + W11[j];
    }

    const float* Xc = X + ((size_t)b * 256 + (size_t)c0) * SLICE;
    float* oc = out + (size_t)b * 12800000 + (size_t)c0 * 50000
                    + (size_t)h * 10000 + d * 100 + w0;

    if (wsum > 0.0f) {
        float g00[CG][2], g01[CG][2], g10[CG][2], g11[CG][2];
        // phase 1: issue all 64 gathers
        #pragma unroll
        for (int cc = 0; cc < CG; ++cc) {
            const float* pc = Xc + (size_t)cc * SLICE;
            #pragma unroll
            for (int j = 0; j < 2; ++j) {
                const float* p = pc + off[j];
                g00[cc][j] = p[0];
                g01[cc][j] = p[1];
                g10[cc][j] = p[320];
                g11[cc][j] = p[321];
            }
        }
        // phase 2: combine + dwordx2 stores
        #pragma unroll
        for (int cc = 0; cc < CG; ++cc) {
            f32x2 res;
            #pragma unroll
            for (int j = 0; j < 2; ++j) {
                float v = W00[j] * g00[cc][j];
                v = fmaf(W01[j], g01[cc][j], v);
                v = fmaf(W10[j], g10[cc][j], v);
                v = fmaf(W11[j], g11[cc][j], v);
                res[j] = v;
            }
            __builtin_nontemporal_store(res, (f32x2*)(oc + (size_t)cc * 50000));
        }
    } else {
        const f32x2 z = {0.0f, 0.0f};
        #pragma unroll
        for (int cc = 0; cc < CG; ++cc) {
            __builtin_nontemporal_store(z, (f32x2*)(oc + (size_t)cc * 50000));
        }
    }
}

extern "C" void kernel_launch(void* const* d_in, const int* in_sizes, int n_in,
                              void* d_out, int out_size, void* d_ws, size_t ws_size,
                              hipStream_t stream) {
    const float* X     = (const float*)d_in[0];   // [4,256,96,320]
    const float* calib = (const float*)d_in[1];   // [4,3,3]
    float* out = (float*)d_out;                   // [4,1280,100,100]

    dim3 grid((NP2 + 255) / 256, 128);            // 98 x (4 batches * 32 groups)
    bev_kernel<<<grid, dim3(256), 0, stream>>>(X, calib, out);
}